// Round 7
// baseline (273.319 us; speedup 1.0000x reference)
//
#include <hip/hip_runtime.h>
#include <math.h>

#define HH 960
#define WW 1280
#define NPIX (HH*WW)
#define BPR (WW/256)             // 5 col-segments per image row
#define NBLK_ROW (NPIX/256)      // 4800 row-mapped blocks for k_pre2
#define NBLK_MAIN (NPIX/(256*2)) // 2400: 2-row x 256-col tiles
#define MM_BLOCKS 512
#define TW 258                   // x0 tile width (256 + 2 halo)
#define PSTRIDE 28               // partial row stride (floats), 16B aligned

// workspace layout (bytes)
#define WS_POSE_OFF    0          // 16 floats
#define WS_BMIN_OFF    128        // 512 floats
#define WS_BMAX_OFF    2176       // 512 floats
#define WS_PARTIAL_OFF 4352      // 2400*28 floats = 268800 B
#define WS_NX_OFF      273152    // NPIX * 2 float4 = 39321600 B -> total ~39.6 MB

__device__ __forceinline__ int clampi(int v, int lo, int hi){ return v<lo?lo:(v>hi?hi:v); }

// ---------------- pre1: pose copy + block min/max partials of depth1 (no atomics) ----------------
__global__ __launch_bounds__(256) void k_pre1(const float* __restrict__ depth1,
                                              const float* __restrict__ pose_in,
                                              float* __restrict__ pose,
                                              float* __restrict__ bmin,
                                              float* __restrict__ bmax){
  int t = threadIdx.x;
  if (blockIdx.x == 0 && t < 16) pose[t] = pose_in[t];
  float mn = INFINITY, mx = 0.f;
  for (int i = blockIdx.x*256 + t; i < NPIX; i += MM_BLOCKS*256){
    float d = depth1[i];
    mn = fminf(mn, d); mx = fmaxf(mx, d);
  }
  #pragma unroll
  for (int off = 32; off; off >>= 1){
    mn = fminf(mn, __shfl_down(mn, off));
    mx = fmaxf(mx, __shfl_down(mx, off));
  }
  __shared__ float smn[4], smx[4];
  int lane = t & 63, wid = t >> 6;
  if (lane == 0){ smn[wid] = mn; smx[wid] = mx; }
  __syncthreads();
  if (t == 0){
    bmin[blockIdx.x] = fminf(fminf(smn[0], smn[1]), fminf(smn[2], smn[3]));
    bmax[blockIdx.x] = fmaxf(fmaxf(smx[0], smx[1]), fmaxf(smx[2], smx[3]));
  }
}

// ---------------- pre2: per-block minmax reduce + write interleaved [n1,d1][x1] float4 pairs ----------------
__global__ __launch_bounds__(256) void k_pre2(const float* __restrict__ depth1,
                                              const float* __restrict__ x1,
                                              const float* __restrict__ Kd,
                                              const float* __restrict__ bmin,
                                              const float* __restrict__ bmax,
                                              float* __restrict__ nx1){
  int t = threadIdx.x;
  float mn = fminf(bmin[t], bmin[t+256]);
  float mx = fmaxf(bmax[t], bmax[t+256]);
  #pragma unroll
  for (int off = 32; off; off >>= 1){
    mn = fminf(mn, __shfl_down(mn, off));
    mx = fmaxf(mx, __shfl_down(mx, off));
  }
  __shared__ float smn[4], smx[4];
  __shared__ float sdmn, sdmx;
  int lane = t & 63, wid = t >> 6;
  if (lane == 0){ smn[wid] = mn; smx[wid] = mx; }
  __syncthreads();
  if (t == 0){
    sdmn = fminf(fminf(smn[0], smn[1]), fminf(smn[2], smn[3]));
    sdmx = fmaxf(fmaxf(smx[0], smx[1]), fmaxf(smx[2], smx[3]));
  }
  __syncthreads();
  float dmn = sdmn, dmx = sdmx;

  int bid = blockIdx.x;
  int py = bid / BPR;
  int px = (bid % BPR)*256 + t;
  float fx = Kd[0], fy = Kd[4], cx = Kd[2], cy = Kd[5];
  float invfx = 1.f/fx, invfy = 1.f/fy;   // single exact div per thread
  float vx[3][3], vy[3][3], vz[3][3];
  #pragma unroll
  for (int dr = 0; dr < 3; dr++){
    int r = clampi(py + dr - 1, 0, HH-1);
    #pragma unroll
    for (int dc = 0; dc < 3; dc++){
      int c = clampi(px + dc - 1, 0, WW-1);
      float d = depth1[r*WW + c];
      vx[dr][dc] = ((float)c - cx)*invfx*d;
      vy[dr][dc] = ((float)r - cy)*invfy*d;
      vz[dr][dc] = d;
    }
  }
  float ax_ = (vx[0][2]-vx[0][0]) + 2.f*(vx[1][2]-vx[1][0]) + (vx[2][2]-vx[2][0]);
  float ay_ = (vy[0][2]-vy[0][0]) + 2.f*(vy[1][2]-vy[1][0]) + (vy[2][2]-vy[2][0]);
  float az_ = (vz[0][2]-vz[0][0]) + 2.f*(vz[1][2]-vz[1][0]) + (vz[2][2]-vz[2][0]);
  float bx_ = (vx[2][0]-vx[0][0]) + 2.f*(vx[2][1]-vx[0][1]) + (vx[2][2]-vx[0][2]);
  float by_ = (vy[2][0]-vy[0][0]) + 2.f*(vy[2][1]-vy[0][1]) + (vy[2][2]-vy[0][2]);
  float bz_ = (vz[2][0]-vz[0][0]) + 2.f*(vz[2][1]-vz[0][1]) + (vz[2][2]-vz[0][2]);
  float nx = ay_*bz_ - az_*by_;
  float ny = az_*bx_ - ax_*bz_;
  float nz = ax_*by_ - ay_*bx_;
  float nrm = sqrtf(nx*nx + ny*ny + nz*nz) + 1e-8f;
  float rn  = __builtin_amdgcn_rcpf(nrm);
  nx *= rn; ny *= rn; nz *= rn;
  float dcen = vz[1][1];
  if (dcen <= dmn || dcen >= dmx){ nx = 0.f; ny = 0.f; nz = 0.f; }
  int idx = py*WW + px;
  const float* q = &x1[idx*3];
  float4 a; a.x = nx;   a.y = ny;   a.z = nz;   a.w = dcen;
  float4 b; b.x = q[0]; b.y = q[1]; b.z = q[2]; b.w = 0.f;
  ((float4*)nx1)[idx*2+0] = a;
  ((float4*)nx1)[idx*2+1] = b;
}

// ---------------- fused per-pixel ICP + RGB accumulation (2-row tile, LDS x0, XCD swizzle) ----------------
__global__ __launch_bounds__(256) void k_main(const float* __restrict__ depth0,
                                              const float* __restrict__ x0,
                                              const float* __restrict__ nx1,
                                              const float* __restrict__ Kd,
                                              const float* __restrict__ pose,
                                              float* __restrict__ partial){
  int t = threadIdx.x;
  // XCD-aware swizzle: contiguous 120-row band per XCD (kept from R6: FETCH 92->29 MB)
  int bid = (blockIdx.x & 7)*(NBLK_MAIN/8) + (blockIdx.x >> 3);
  int pr = bid / BPR;
  int cs = bid % BPR;
  int py0 = pr*2;
  int colbase = cs*256 - 1;
  int px = cs*256 + t;

  __shared__ float tile[4*TW*3];    // 12384 B
  for (int s = t; s < 4*TW; s += 256){
    int r = s / TW, c = s - r*TW;
    int gr = clampi(py0 - 1 + r, 0, HH-1);
    int gc = clampi(colbase + c, 0, WW-1);
    const float* q = &x0[(gr*WW + gc)*3];
    tile[s*3+0] = q[0]; tile[s*3+1] = q[1]; tile[s*3+2] = q[2];
  }
  __syncthreads();

  float fx = Kd[0], fy = Kd[4], cx = Kd[2], cy = Kd[5];
  float inv_fx = 1.f/fx, inv_fy = 1.f/fy;
  float R00=pose[0], R01=pose[1], R02=pose[2],  tx=pose[3];
  float R10=pose[4], R11=pose[5], R12=pose[6],  ty=pose[7];
  float R20=pose[8], R21=pose[9], R22=pose[10], tz=pose[11];

  float acc[27];
  #pragma unroll
  for (int k = 0; k < 27; k++) acc[k] = 0.f;

  const float4* nx4 = (const float4*)nx1;

  // per-thread 3x3x3-channel window rows (9 contiguous floats per row), loaded once
  float rb[4][9];
  #pragma unroll
  for (int r = 0; r < 4; r++)
    #pragma unroll
    for (int q = 0; q < 9; q++)
      rb[r][q] = tile[(r*TW + t)*3 + q];
  // shared column diffs (col2-col0) per row per channel
  float cdf[4][3];
  #pragma unroll
  for (int r = 0; r < 4; r++)
    #pragma unroll
    for (int ch = 0; ch < 3; ch++)
      cdf[r][ch] = rb[r][6+ch] - rb[r][ch];

  // prefetch both depth0 values (independent loads early)
  int idx0 = py0*WW + px;
  float d0v[2];
  d0v[0] = depth0[idx0];
  d0v[1] = depth0[idx0 + WW];

  #pragma unroll
  for (int kp = 0; kp < 2; kp++){
    int py = py0 + kp;
    int idx = idx0 + kp*WW;

    float d0 = d0v[kp];
    bool m0 = d0 > 0.f;
    float v0x = ((float)px - cx)*inv_fx*d0;
    float v0y = ((float)py - cy)*inv_fy*d0;
    float v0z = d0;
    float X = R00*v0x + R01*v0y + R02*v0z + tx;
    float Y = R10*v0x + R11*v0y + R12*v0z + ty;
    float Z = R20*v0x + R21*v0y + R22*v0z + tz;
    // 1/Z via rcp + one Newton step (drives u,v indices -> keep tight)
    float invZ = __builtin_amdgcn_rcpf(Z);
    invZ = invZ*(2.0f - Z*invZ);
    float u = X*invZ*fx + cx;
    float v = Y*invZ*fy + cy;
    bool inview = (u > 0.f) && (u < (float)(WW-1)) && (v > 0.f) && (v < (float)(HH-1)) && (Z > 0.f);

    float uc = fminf(fmaxf(u, 0.f), (float)(WW-1));
    float vc = fminf(fmaxf(v, 0.f), (float)(HH-1));
    float u0f = floorf(uc), v0f = floorf(vc);
    float wu = uc - u0f, wv = vc - v0f;
    int u0i = clampi((int)u0f, 0, WW-1);
    int v0i = clampi((int)v0f, 0, HH-1);
    int u1i = min(u0i + 1, WW-1);
    int v1i = min(v0i + 1, HH-1);
    int i00 = v0i*WW + u0i, i01 = v0i*WW + u1i, i10 = v1i*WW + u0i, i11 = v1i*WW + u1i;
    float w00 = (1.f-wu)*(1.f-wv), w01 = wu*(1.f-wv), w10 = (1.f-wu)*wv, w11 = wu*wv;

    float4 n00 = nx4[i00*2], c00 = nx4[i00*2+1];
    float4 n01 = nx4[i01*2], c01 = nx4[i01*2+1];
    float4 n10 = nx4[i10*2], c10 = nx4[i10*2+1];
    float4 n11 = nx4[i11*2], c11 = nx4[i11*2+1];

    // factored vertex interpolation
    float t0 = w00*n00.w, t1 = w01*n01.w, t2 = w10*n10.w, t3 = w11*n11.w;
    float u0c = ((float)u0i - cx)*inv_fx, u1c = ((float)u1i - cx)*inv_fx;
    float v0c = ((float)v0i - cy)*inv_fy, v1c = ((float)v1i - cy)*inv_fy;
    float s2 = (t0+t1)+(t2+t3);
    float s0 = u0c*(t0+t2) + u1c*(t1+t3);
    float s1 = v0c*(t0+t1) + v1c*(t2+t3);
    float nx = n00.x*w00 + n01.x*w01 + n10.x*w10 + n11.x*w11;
    float ny = n00.y*w00 + n01.y*w01 + n10.y*w10 + n11.y*w11;
    float nz = n00.z*w00 + n01.z*w01 + n10.z*w10 + n11.z*w11;

    float dfx = X - s0, dfy = Y - s1, dfz = Z - s2;
    bool valid = inview && m0 && (s2 > 0.f) && (dfx*dfx + dfy*dfy + dfz*dfz < 0.01f);
    float res = 0.f;
    float J[6] = {0.f,0.f,0.f,0.f,0.f,0.f};
    if (valid){
      res = nx*dfx + ny*dfy + nz*dfz;
      J[0] = Y*nz - Z*ny;
      J[1] = Z*nx - X*nz;
      J[2] = X*ny - Y*nx;
      J[3] = nx; J[4] = ny; J[5] = nz;
    }
    float axv = fabsf(res);
    float rho = (axv <= 0.02f) ? axv*axv : (0.04f*axv - 0.0004f);
    float xs  = (axv < 1e-8f) ? 1.f : axv;
    float hw  = sqrtf(rho + 1e-16f) * __builtin_amdgcn_rcpf(xs);
    float wr  = hw*res;
    float wJ[6];
    #pragma unroll
    for (int i = 0; i < 6; i++) wJ[i] = hw*J[i];
    {
      int k = 0;
      #pragma unroll
      for (int i = 0; i < 6; i++)
        #pragma unroll
        for (int j = i; j < 6; j++)
          acc[k++] += wJ[i]*wJ[j];
      #pragma unroll
      for (int i = 0; i < 6; i++) acc[21+i] += wJ[i]*wr;
    }

    if (inview && m0){
      float xw[3];
      xw[0] = c00.x*w00 + c01.x*w01 + c10.x*w10 + c11.x*w11;
      xw[1] = c00.y*w00 + c01.y*w01 + c10.y*w10 + c11.y*w11;
      xw[2] = c00.z*w00 + c01.z*w01 + c10.z*w10 + c11.z*w11;

      // gradient Gram scalars via register window; rsq instead of sqrt+2 div
      float ga = 0.f, gb = 0.f, gc2 = 0.f, rx = 0.f, ry = 0.f;
      #pragma unroll
      for (int ch = 0; ch < 3; ch++){
        float dx = cdf[kp][ch] + 2.f*cdf[kp+1][ch] + cdf[kp+2][ch];
        float dy = (rb[kp+2][ch]-rb[kp][ch]) + 2.f*(rb[kp+2][3+ch]-rb[kp][3+ch]) + (rb[kp+2][6+ch]-rb[kp][6+ch]);
        float rinv = __builtin_amdgcn_rsqf(dx*dx + dy*dy + 1e-8f);
        float gx = dx*rinv, gy = dy*rinv;
        float rr = xw[ch] - rb[kp+1][3+ch];
        ga  += gx*gx; gb += gx*gy; gc2 += gy*gy;
        rx  += gx*rr; ry += gy*rr;
      }
      ga *= 1e-6f; gb *= 1e-6f; gc2 *= 1e-6f; rx *= 1e-6f; ry *= 1e-6f;

      float invD = __builtin_amdgcn_rcpf(d0), invD2 = invD*invD;
      float xy = v0x*v0y;
      float Jx[6] = { fx*(-invD2*xy), fx*(1.f + v0x*v0x*invD2), fx*(-v0y*invD), fx*invD, 0.f, fx*(-invD2*v0x) };
      float Jy[6] = { fy*(-1.f - invD2*v0y*v0y), fy*(xy*invD2), fy*(v0x*invD), 0.f, fy*invD, fy*(-invD2*v0y) };
      float P[6], Q[6];
      #pragma unroll
      for (int i = 0; i < 6; i++){ P[i] = ga*Jx[i] + gb*Jy[i]; Q[i] = gb*Jx[i] + gc2*Jy[i]; }
      int k = 0;
      #pragma unroll
      for (int i = 0; i < 6; i++)
        #pragma unroll
        for (int j = i; j < 6; j++)
          acc[k++] += Jx[j]*P[i] + Jy[j]*Q[i];
      #pragma unroll
      for (int i = 0; i < 6; i++) acc[21+i] += Jx[i]*rx + Jy[i]*ry;
    }
  }

  // block reduction: wave shfl -> LDS -> 27 floats per block (stride-28 rows)
  __shared__ float lds[108];
  int lane = t & 63;
  int wid  = t >> 6;
  #pragma unroll
  for (int k = 0; k < 27; k++){
    float vv = acc[k];
    vv += __shfl_down(vv, 32); vv += __shfl_down(vv, 16); vv += __shfl_down(vv, 8);
    vv += __shfl_down(vv, 4);  vv += __shfl_down(vv, 2);  vv += __shfl_down(vv, 1);
    if (lane == 0) lds[wid*27 + k] = vv;
  }
  __syncthreads();
  if (t < 27)
    partial[bid*PSTRIDE + t] = lds[t] + lds[27+t] + lds[54+t] + lds[81+t];
  else if (t == 27)
    partial[bid*PSTRIDE + 27] = 0.f;
}

// ---------------- final reduce + damped 6x6 solve + pose update (double) ----------------
__global__ __launch_bounds__(256) void k_solve(const float* __restrict__ partial,
                                               float* __restrict__ pose,
                                               float* __restrict__ outp){
  int t = threadIdx.x;
  double acc[PSTRIDE];
  #pragma unroll
  for (int k = 0; k < PSTRIDE; k++) acc[k] = 0.0;
  const float4* p4 = (const float4*)partial;
  for (int r = t; r < NBLK_MAIN; r += 256){
    #pragma unroll
    for (int q = 0; q < 7; q++){
      float4 vv = p4[r*7 + q];
      acc[q*4+0] += (double)vv.x;
      acc[q*4+1] += (double)vv.y;
      acc[q*4+2] += (double)vv.z;
      acc[q*4+3] += (double)vv.w;
    }
  }
  __shared__ double lds[4*PSTRIDE];
  int lane = t & 63, wid = t >> 6;
  #pragma unroll
  for (int k = 0; k < PSTRIDE; k++){
    double vv = acc[k];
    vv += __shfl_down(vv, 32); vv += __shfl_down(vv, 16); vv += __shfl_down(vv, 8);
    vv += __shfl_down(vv, 4);  vv += __shfl_down(vv, 2);  vv += __shfl_down(vv, 1);
    if (lane == 0) lds[wid*PSTRIDE + k] = vv;
  }
  __syncthreads();
  if (t == 0){
    double s[PSTRIDE];
    #pragma unroll
    for (int k = 0; k < PSTRIDE; k++)
      s[k] = lds[k] + lds[PSTRIDE+k] + lds[2*PSTRIDE+k] + lds[3*PSTRIDE+k];
    double Hm[6][6], b[6];
    {
      int k = 0;
      for (int i = 0; i < 6; i++)
        for (int j = i; j < 6; j++){ Hm[i][j] = s[k]; Hm[j][i] = s[k]; k++; }
      for (int i = 0; i < 6; i++) b[i] = s[21+i];
    }
    double tr = Hm[0][0]+Hm[1][1]+Hm[2][2]+Hm[3][3]+Hm[4][4]+Hm[5][5];
    for (int i = 0; i < 6; i++) Hm[i][i] += tr*0.001;
    double A[6][7];
    for (int i = 0; i < 6; i++){
      for (int j = 0; j < 6; j++) A[i][j] = Hm[i][j];
      A[i][6] = b[i];
    }
    for (int c = 0; c < 6; c++){
      int piv = c; double best = fabs(A[c][c]);
      for (int r = c+1; r < 6; r++){ double a = fabs(A[r][c]); if (a > best){ best = a; piv = r; } }
      if (piv != c)
        for (int j = 0; j < 7; j++){ double tv = A[c][j]; A[c][j] = A[piv][j]; A[piv][j] = tv; }
      double inv = 1.0/A[c][c];
      for (int r = 0; r < 6; r++){
        if (r == c) continue;
        double f = A[r][c]*inv;
        for (int j = c; j < 7; j++) A[r][j] -= f*A[c][j];
      }
    }
    double xi[6];
    for (int i = 0; i < 6; i++) xi[i] = A[i][6]/A[i][i];
    double wx = -xi[0], wy = -xi[1], wz = -xi[2];
    double th2 = wx*wx + wy*wy + wz*wz;
    if (th2 < 1e-30) th2 = 1e-30;
    double th = sqrt(th2);
    double dR[3][3];
    if (th <= 1e-10){
      dR[0][0]=1; dR[0][1]=0; dR[0][2]=0;
      dR[1][0]=0; dR[1][1]=1; dR[1][2]=0;
      dR[2][0]=0; dR[2][1]=0; dR[2][2]=1;
    } else {
      double sa = sin(th)/th;
      double sb = (1.0 - cos(th))/th2;
      double Wm[3][3] = {{0,-wz,wy},{wz,0,-wx},{-wy,wx,0}};
      double W2[3][3];
      for (int i = 0; i < 3; i++)
        for (int j = 0; j < 3; j++)
          W2[i][j] = Wm[i][0]*Wm[0][j] + Wm[i][1]*Wm[1][j] + Wm[i][2]*Wm[2][j];
      for (int i = 0; i < 3; i++)
        for (int j = 0; j < 3; j++)
          dR[i][j] = (i==j ? 1.0 : 0.0) + sa*Wm[i][j] + sb*W2[i][j];
    }
    double dt[3];
    for (int i = 0; i < 3; i++)
      dt[i] = -(dR[i][0]*xi[3] + dR[i][1]*xi[4] + dR[i][2]*xi[5]);
    double Ro[3][3], to[3];
    for (int i = 0; i < 3; i++){
      for (int j = 0; j < 3; j++) Ro[i][j] = (double)pose[i*4+j];
      to[i] = (double)pose[i*4+3];
    }
    double Rn[3][3], tn[3];
    for (int i = 0; i < 3; i++){
      for (int j = 0; j < 3; j++)
        Rn[i][j] = dR[i][0]*Ro[0][j] + dR[i][1]*Ro[1][j] + dR[i][2]*Ro[2][j];
      tn[i] = dR[i][0]*to[0] + dR[i][1]*to[1] + dR[i][2]*to[2] + dt[i];
    }
    float o16[16];
    for (int i = 0; i < 3; i++){
      for (int j = 0; j < 3; j++) o16[i*4+j] = (float)Rn[i][j];
      o16[i*4+3] = (float)tn[i];
    }
    o16[12] = 0.f; o16[13] = 0.f; o16[14] = 0.f; o16[15] = 1.f;
    for (int k = 0; k < 16; k++){ pose[k] = o16[k]; outp[k] = o16[k]; }
  }
}

extern "C" void kernel_launch(void* const* d_in, const int* in_sizes, int n_in,
                              void* d_out, int out_size, void* d_ws, size_t ws_size,
                              hipStream_t stream) {
  const float* pose10 = (const float*)d_in[0];
  const float* depth0 = (const float*)d_in[1];
  const float* depth1 = (const float*)d_in[2];
  const float* x0     = (const float*)d_in[3];
  const float* x1     = (const float*)d_in[4];
  const float* Kd     = (const float*)d_in[5];
  char* ws = (char*)d_ws;
  float* pose    = (float*)(ws + WS_POSE_OFF);
  float* bmin    = (float*)(ws + WS_BMIN_OFF);
  float* bmax    = (float*)(ws + WS_BMAX_OFF);
  float* partial = (float*)(ws + WS_PARTIAL_OFF);
  float* nx1     = (float*)(ws + WS_NX_OFF);
  float* outp    = (float*)d_out;

  hipLaunchKernelGGL(k_pre1, dim3(MM_BLOCKS), dim3(256), 0, stream,
                     depth1, pose10, pose, bmin, bmax);
  hipLaunchKernelGGL(k_pre2, dim3(NBLK_ROW),  dim3(256), 0, stream,
                     depth1, x1, Kd, bmin, bmax, nx1);
  for (int it = 0; it < 3; it++){
    hipLaunchKernelGGL(k_main,  dim3(NBLK_MAIN), dim3(256), 0, stream,
                       depth0, x0, nx1, Kd, pose, partial);
    hipLaunchKernelGGL(k_solve, dim3(1),         dim3(256), 0, stream, partial, pose, outp);
  }
}

// Round 8
// 252.486 us; speedup vs baseline: 1.0825x; 1.0825x over previous
//
#include <hip/hip_runtime.h>
#include <math.h>

#define HH 960
#define WW 1280
#define NPIX (HH*WW)
#define BPR (WW/256)             // 5 col-segments per image row
#define NBLK_ROW (NPIX/256)      // 4800 row-mapped blocks for k_pre2
#define NBLK_MAIN (NPIX/(256*2)) // 2400: 2-row x 256-col tiles
#define MM_BLOCKS 512
#define TW 258                   // x0 tile width (256 + 2 halo)
#define PSTRIDE 28               // partial row stride (floats), 16B aligned

// workspace layout (bytes)
#define WS_POSE_OFF    0          // 16 floats
#define WS_BMIN_OFF    128        // 512 floats
#define WS_BMAX_OFF    2176       // 512 floats
#define WS_PARTIAL_OFF 4352      // 2400*28 floats = 268800 B
#define WS_NX_OFF      273152    // NPIX * 2 float4 = 39321600 B -> total ~39.6 MB

__device__ __forceinline__ int clampi(int v, int lo, int hi){ return v<lo?lo:(v>hi?hi:v); }

// ---------------- pre1: pose copy + block min/max partials of depth1 (no atomics) ----------------
__global__ __launch_bounds__(256) void k_pre1(const float* __restrict__ depth1,
                                              const float* __restrict__ pose_in,
                                              float* __restrict__ pose,
                                              float* __restrict__ bmin,
                                              float* __restrict__ bmax){
  int t = threadIdx.x;
  if (blockIdx.x == 0 && t < 16) pose[t] = pose_in[t];
  float mn = INFINITY, mx = 0.f;
  for (int i = blockIdx.x*256 + t; i < NPIX; i += MM_BLOCKS*256){
    float d = depth1[i];
    mn = fminf(mn, d); mx = fmaxf(mx, d);
  }
  #pragma unroll
  for (int off = 32; off; off >>= 1){
    mn = fminf(mn, __shfl_down(mn, off));
    mx = fmaxf(mx, __shfl_down(mx, off));
  }
  __shared__ float smn[4], smx[4];
  int lane = t & 63, wid = t >> 6;
  if (lane == 0){ smn[wid] = mn; smx[wid] = mx; }
  __syncthreads();
  if (t == 0){
    bmin[blockIdx.x] = fminf(fminf(smn[0], smn[1]), fminf(smn[2], smn[3]));
    bmax[blockIdx.x] = fmaxf(fmaxf(smx[0], smx[1]), fmaxf(smx[2], smx[3]));
  }
}

// ---------------- pre2: per-block minmax reduce + write interleaved [n1,d1][x1] float4 pairs ----------------
__global__ __launch_bounds__(256) void k_pre2(const float* __restrict__ depth1,
                                              const float* __restrict__ x1,
                                              const float* __restrict__ Kd,
                                              const float* __restrict__ bmin,
                                              const float* __restrict__ bmax,
                                              float* __restrict__ nx1){
  int t = threadIdx.x;
  float mn = fminf(bmin[t], bmin[t+256]);
  float mx = fmaxf(bmax[t], bmax[t+256]);
  #pragma unroll
  for (int off = 32; off; off >>= 1){
    mn = fminf(mn, __shfl_down(mn, off));
    mx = fmaxf(mx, __shfl_down(mx, off));
  }
  __shared__ float smn[4], smx[4];
  __shared__ float sdmn, sdmx;
  int lane = t & 63, wid = t >> 6;
  if (lane == 0){ smn[wid] = mn; smx[wid] = mx; }
  __syncthreads();
  if (t == 0){
    sdmn = fminf(fminf(smn[0], smn[1]), fminf(smn[2], smn[3]));
    sdmx = fmaxf(fmaxf(smx[0], smx[1]), fmaxf(smx[2], smx[3]));
  }
  __syncthreads();
  float dmn = sdmn, dmx = sdmx;

  int bid = blockIdx.x;
  int py = bid / BPR;
  int px = (bid % BPR)*256 + t;
  float fx = Kd[0], fy = Kd[4], cx = Kd[2], cy = Kd[5];
  float invfx = 1.f/fx, invfy = 1.f/fy;
  float vx[3][3], vy[3][3], vz[3][3];
  #pragma unroll
  for (int dr = 0; dr < 3; dr++){
    int r = clampi(py + dr - 1, 0, HH-1);
    #pragma unroll
    for (int dc = 0; dc < 3; dc++){
      int c = clampi(px + dc - 1, 0, WW-1);
      float d = depth1[r*WW + c];
      vx[dr][dc] = ((float)c - cx)*invfx*d;
      vy[dr][dc] = ((float)r - cy)*invfy*d;
      vz[dr][dc] = d;
    }
  }
  float ax_ = (vx[0][2]-vx[0][0]) + 2.f*(vx[1][2]-vx[1][0]) + (vx[2][2]-vx[2][0]);
  float ay_ = (vy[0][2]-vy[0][0]) + 2.f*(vy[1][2]-vy[1][0]) + (vy[2][2]-vy[2][0]);
  float az_ = (vz[0][2]-vz[0][0]) + 2.f*(vz[1][2]-vz[1][0]) + (vz[2][2]-vz[2][0]);
  float bx_ = (vx[2][0]-vx[0][0]) + 2.f*(vx[2][1]-vx[0][1]) + (vx[2][2]-vx[0][2]);
  float by_ = (vy[2][0]-vy[0][0]) + 2.f*(vy[2][1]-vy[0][1]) + (vy[2][2]-vy[0][2]);
  float bz_ = (vz[2][0]-vz[0][0]) + 2.f*(vz[2][1]-vz[0][1]) + (vz[2][2]-vz[0][2]);
  float nx = ay_*bz_ - az_*by_;
  float ny = az_*bx_ - ax_*bz_;
  float nz = ax_*by_ - ay_*bx_;
  float nrm = sqrtf(nx*nx + ny*ny + nz*nz) + 1e-8f;
  float rn  = __builtin_amdgcn_rcpf(nrm);
  nx *= rn; ny *= rn; nz *= rn;
  float dcen = vz[1][1];
  if (dcen <= dmn || dcen >= dmx){ nx = 0.f; ny = 0.f; nz = 0.f; }
  int idx = py*WW + px;
  const float* q = &x1[idx*3];
  float4 a; a.x = nx;   a.y = ny;   a.z = nz;   a.w = dcen;
  float4 b; b.x = q[0]; b.y = q[1]; b.z = q[2]; b.w = 0.f;
  ((float4*)nx1)[idx*2+0] = a;
  ((float4*)nx1)[idx*2+1] = b;
}

// ---------------- fused per-pixel ICP + RGB accumulation (2-row tile, LDS x0, XCD swizzle) ----------------
// R8: R6 structure (direct LDS tile reads, low VGPR) + register-neutral rcp/rsq swaps only.
__global__ __launch_bounds__(256) void k_main(const float* __restrict__ depth0,
                                              const float* __restrict__ x0,
                                              const float* __restrict__ nx1,
                                              const float* __restrict__ Kd,
                                              const float* __restrict__ pose,
                                              float* __restrict__ partial){
  int t = threadIdx.x;
  // XCD-aware swizzle: contiguous 120-row band per XCD (R6: FETCH 92->29 MB)
  int bid = (blockIdx.x & 7)*(NBLK_MAIN/8) + (blockIdx.x >> 3);
  int pr = bid / BPR;
  int cs = bid % BPR;
  int py0 = pr*2;
  int colbase = cs*256 - 1;
  int px = cs*256 + t;

  __shared__ float tile[4*TW*3];    // 12384 B
  for (int s = t; s < 4*TW; s += 256){
    int r = s / TW, c = s - r*TW;
    int gr = clampi(py0 - 1 + r, 0, HH-1);
    int gc = clampi(colbase + c, 0, WW-1);
    const float* q = &x0[(gr*WW + gc)*3];
    tile[s*3+0] = q[0]; tile[s*3+1] = q[1]; tile[s*3+2] = q[2];
  }

  // prefetch both depth0 values before the barrier (independent of LDS)
  int idx0 = py0*WW + px;
  float d0a = depth0[idx0];
  float d0b = depth0[idx0 + WW];
  __syncthreads();

  float fx = Kd[0], fy = Kd[4], cx = Kd[2], cy = Kd[5];
  float inv_fx = 1.f/fx, inv_fy = 1.f/fy;
  float R00=pose[0], R01=pose[1], R02=pose[2],  tx=pose[3];
  float R10=pose[4], R11=pose[5], R12=pose[6],  ty=pose[7];
  float R20=pose[8], R21=pose[9], R22=pose[10], tz=pose[11];

  float acc[27];
  #pragma unroll
  for (int k = 0; k < 27; k++) acc[k] = 0.f;

  const float4* nx4 = (const float4*)nx1;

  #pragma unroll
  for (int kp = 0; kp < 2; kp++){
    int py = py0 + kp;

    float d0 = (kp == 0) ? d0a : d0b;
    bool m0 = d0 > 0.f;
    float v0x = ((float)px - cx)*inv_fx*d0;
    float v0y = ((float)py - cy)*inv_fy*d0;
    float v0z = d0;
    float X = R00*v0x + R01*v0y + R02*v0z + tx;
    float Y = R10*v0x + R11*v0y + R12*v0z + ty;
    float Z = R20*v0x + R21*v0y + R22*v0z + tz;
    // 1/Z via rcp + one Newton step (drives u,v indices)
    float invZ = __builtin_amdgcn_rcpf(Z);
    invZ = invZ*(2.0f - Z*invZ);
    float u = X*invZ*fx + cx;
    float v = Y*invZ*fy + cy;
    bool inview = (u > 0.f) && (u < (float)(WW-1)) && (v > 0.f) && (v < (float)(HH-1)) && (Z > 0.f);

    float uc = fminf(fmaxf(u, 0.f), (float)(WW-1));
    float vc = fminf(fmaxf(v, 0.f), (float)(HH-1));
    float u0f = floorf(uc), v0f = floorf(vc);
    float wu = uc - u0f, wv = vc - v0f;
    int u0i = clampi((int)u0f, 0, WW-1);
    int v0i = clampi((int)v0f, 0, HH-1);
    int u1i = min(u0i + 1, WW-1);
    int v1i = min(v0i + 1, HH-1);
    int i00 = v0i*WW + u0i, i01 = v0i*WW + u1i, i10 = v1i*WW + u0i, i11 = v1i*WW + u1i;
    float w00 = (1.f-wu)*(1.f-wv), w01 = wu*(1.f-wv), w10 = (1.f-wu)*wv, w11 = wu*wv;

    float4 n00 = nx4[i00*2], c00 = nx4[i00*2+1];
    float4 n01 = nx4[i01*2], c01 = nx4[i01*2+1];
    float4 n10 = nx4[i10*2], c10 = nx4[i10*2+1];
    float4 n11 = nx4[i11*2], c11 = nx4[i11*2+1];

    // factored vertex interpolation
    float t0 = w00*n00.w, t1 = w01*n01.w, t2 = w10*n10.w, t3 = w11*n11.w;
    float u0c = ((float)u0i - cx)*inv_fx, u1c = ((float)u1i - cx)*inv_fx;
    float v0c = ((float)v0i - cy)*inv_fy, v1c = ((float)v1i - cy)*inv_fy;
    float s2 = (t0+t1)+(t2+t3);
    float s0 = u0c*(t0+t2) + u1c*(t1+t3);
    float s1 = v0c*(t0+t1) + v1c*(t2+t3);
    float nx = n00.x*w00 + n01.x*w01 + n10.x*w10 + n11.x*w11;
    float ny = n00.y*w00 + n01.y*w01 + n10.y*w10 + n11.y*w11;
    float nz = n00.z*w00 + n01.z*w01 + n10.z*w10 + n11.z*w11;

    float dfx = X - s0, dfy = Y - s1, dfz = Z - s2;
    bool valid = inview && m0 && (s2 > 0.f) && (dfx*dfx + dfy*dfy + dfz*dfz < 0.01f);
    float res = 0.f;
    float J[6] = {0.f,0.f,0.f,0.f,0.f,0.f};
    if (valid){
      res = nx*dfx + ny*dfy + nz*dfz;
      J[0] = Y*nz - Z*ny;
      J[1] = Z*nx - X*nz;
      J[2] = X*ny - Y*nx;
      J[3] = nx; J[4] = ny; J[5] = nz;
    }
    float axv = fabsf(res);
    float rho = (axv <= 0.02f) ? axv*axv : (0.04f*axv - 0.0004f);
    float xs  = (axv < 1e-8f) ? 1.f : axv;
    float hw  = sqrtf(rho + 1e-16f) * __builtin_amdgcn_rcpf(xs);
    float wr  = hw*res;
    float wJ[6];
    #pragma unroll
    for (int i = 0; i < 6; i++) wJ[i] = hw*J[i];
    {
      int k = 0;
      #pragma unroll
      for (int i = 0; i < 6; i++)
        #pragma unroll
        for (int j = i; j < 6; j++)
          acc[k++] += wJ[i]*wJ[j];
      #pragma unroll
      for (int i = 0; i < 6; i++) acc[21+i] += wJ[i]*wr;
    }

    if (inview && m0){
      float xw[3];
      xw[0] = c00.x*w00 + c01.x*w01 + c10.x*w10 + c11.x*w11;
      xw[1] = c00.y*w00 + c01.y*w01 + c10.y*w10 + c11.y*w11;
      xw[2] = c00.z*w00 + c01.z*w01 + c10.z*w10 + c11.z*w11;

      // gradient Gram scalars; direct LDS reads (R6), rsq instead of sqrt+2div (R7)
      float ga = 0.f, gb = 0.f, gc2 = 0.f, rx = 0.f, ry = 0.f;
      #pragma unroll
      for (int ch = 0; ch < 3; ch++){
        float p00 = tile[((kp+0)*TW + (t+0))*3 + ch];
        float p01 = tile[((kp+0)*TW + (t+1))*3 + ch];
        float p02 = tile[((kp+0)*TW + (t+2))*3 + ch];
        float p10 = tile[((kp+1)*TW + (t+0))*3 + ch];
        float p11 = tile[((kp+1)*TW + (t+1))*3 + ch];
        float p12 = tile[((kp+1)*TW + (t+2))*3 + ch];
        float p20 = tile[((kp+2)*TW + (t+0))*3 + ch];
        float p21 = tile[((kp+2)*TW + (t+1))*3 + ch];
        float p22 = tile[((kp+2)*TW + (t+2))*3 + ch];
        float dx = (p02-p00) + 2.f*(p12-p10) + (p22-p20);
        float dy = (p20-p00) + 2.f*(p21-p01) + (p22-p02);
        float rinv = __builtin_amdgcn_rsqf(dx*dx + dy*dy + 1e-8f);
        float gx = dx*rinv, gy = dy*rinv;
        float rr = xw[ch] - p11;
        ga  += gx*gx; gb += gx*gy; gc2 += gy*gy;
        rx  += gx*rr; ry += gy*rr;
      }
      ga *= 1e-6f; gb *= 1e-6f; gc2 *= 1e-6f; rx *= 1e-6f; ry *= 1e-6f;

      float invD = __builtin_amdgcn_rcpf(d0), invD2 = invD*invD;
      float xy = v0x*v0y;
      float Jx[6] = { fx*(-invD2*xy), fx*(1.f + v0x*v0x*invD2), fx*(-v0y*invD), fx*invD, 0.f, fx*(-invD2*v0x) };
      float Jy[6] = { fy*(-1.f - invD2*v0y*v0y), fy*(xy*invD2), fy*(v0x*invD), 0.f, fy*invD, fy*(-invD2*v0y) };
      float P[6], Q[6];
      #pragma unroll
      for (int i = 0; i < 6; i++){ P[i] = ga*Jx[i] + gb*Jy[i]; Q[i] = gb*Jx[i] + gc2*Jy[i]; }
      int k = 0;
      #pragma unroll
      for (int i = 0; i < 6; i++)
        #pragma unroll
        for (int j = i; j < 6; j++)
          acc[k++] += Jx[j]*P[i] + Jy[j]*Q[i];
      #pragma unroll
      for (int i = 0; i < 6; i++) acc[21+i] += Jx[i]*rx + Jy[i]*ry;
    }
  }

  // block reduction: wave shfl -> LDS -> 27 floats per block (stride-28 rows)
  __shared__ float lds[108];
  int lane = t & 63;
  int wid  = t >> 6;
  #pragma unroll
  for (int k = 0; k < 27; k++){
    float vv = acc[k];
    vv += __shfl_down(vv, 32); vv += __shfl_down(vv, 16); vv += __shfl_down(vv, 8);
    vv += __shfl_down(vv, 4);  vv += __shfl_down(vv, 2);  vv += __shfl_down(vv, 1);
    if (lane == 0) lds[wid*27 + k] = vv;
  }
  __syncthreads();
  if (t < 27)
    partial[bid*PSTRIDE + t] = lds[t] + lds[27+t] + lds[54+t] + lds[81+t];
  else if (t == 27)
    partial[bid*PSTRIDE + 27] = 0.f;
}

// ---------------- final reduce + damped 6x6 solve + pose update (double) ----------------
__global__ __launch_bounds__(256) void k_solve(const float* __restrict__ partial,
                                               float* __restrict__ pose,
                                               float* __restrict__ outp){
  int t = threadIdx.x;
  double acc[PSTRIDE];
  #pragma unroll
  for (int k = 0; k < PSTRIDE; k++) acc[k] = 0.0;
  const float4* p4 = (const float4*)partial;
  for (int r = t; r < NBLK_MAIN; r += 256){
    #pragma unroll
    for (int q = 0; q < 7; q++){
      float4 vv = p4[r*7 + q];
      acc[q*4+0] += (double)vv.x;
      acc[q*4+1] += (double)vv.y;
      acc[q*4+2] += (double)vv.z;
      acc[q*4+3] += (double)vv.w;
    }
  }
  __shared__ double lds[4*PSTRIDE];
  int lane = t & 63, wid = t >> 6;
  #pragma unroll
  for (int k = 0; k < PSTRIDE; k++){
    double vv = acc[k];
    vv += __shfl_down(vv, 32); vv += __shfl_down(vv, 16); vv += __shfl_down(vv, 8);
    vv += __shfl_down(vv, 4);  vv += __shfl_down(vv, 2);  vv += __shfl_down(vv, 1);
    if (lane == 0) lds[wid*PSTRIDE + k] = vv;
  }
  __syncthreads();
  if (t == 0){
    double s[PSTRIDE];
    #pragma unroll
    for (int k = 0; k < PSTRIDE; k++)
      s[k] = lds[k] + lds[PSTRIDE+k] + lds[2*PSTRIDE+k] + lds[3*PSTRIDE+k];
    double Hm[6][6], b[6];
    {
      int k = 0;
      for (int i = 0; i < 6; i++)
        for (int j = i; j < 6; j++){ Hm[i][j] = s[k]; Hm[j][i] = s[k]; k++; }
      for (int i = 0; i < 6; i++) b[i] = s[21+i];
    }
    double tr = Hm[0][0]+Hm[1][1]+Hm[2][2]+Hm[3][3]+Hm[4][4]+Hm[5][5];
    for (int i = 0; i < 6; i++) Hm[i][i] += tr*0.001;
    double A[6][7];
    for (int i = 0; i < 6; i++){
      for (int j = 0; j < 6; j++) A[i][j] = Hm[i][j];
      A[i][6] = b[i];
    }
    for (int c = 0; c < 6; c++){
      int piv = c; double best = fabs(A[c][c]);
      for (int r = c+1; r < 6; r++){ double a = fabs(A[r][c]); if (a > best){ best = a; piv = r; } }
      if (piv != c)
        for (int j = 0; j < 7; j++){ double tv = A[c][j]; A[c][j] = A[piv][j]; A[piv][j] = tv; }
      double inv = 1.0/A[c][c];
      for (int r = 0; r < 6; r++){
        if (r == c) continue;
        double f = A[r][c]*inv;
        for (int j = c; j < 7; j++) A[r][j] -= f*A[c][j];
      }
    }
    double xi[6];
    for (int i = 0; i < 6; i++) xi[i] = A[i][6]/A[i][i];
    double wx = -xi[0], wy = -xi[1], wz = -xi[2];
    double th2 = wx*wx + wy*wy + wz*wz;
    if (th2 < 1e-30) th2 = 1e-30;
    double th = sqrt(th2);
    double dR[3][3];
    if (th <= 1e-10){
      dR[0][0]=1; dR[0][1]=0; dR[0][2]=0;
      dR[1][0]=0; dR[1][1]=1; dR[1][2]=0;
      dR[2][0]=0; dR[2][1]=0; dR[2][2]=1;
    } else {
      double sa = sin(th)/th;
      double sb = (1.0 - cos(th))/th2;
      double Wm[3][3] = {{0,-wz,wy},{wz,0,-wx},{-wy,wx,0}};
      double W2[3][3];
      for (int i = 0; i < 3; i++)
        for (int j = 0; j < 3; j++)
          W2[i][j] = Wm[i][0]*Wm[0][j] + Wm[i][1]*Wm[1][j] + Wm[i][2]*Wm[2][j];
      for (int i = 0; i < 3; i++)
        for (int j = 0; j < 3; j++)
          dR[i][j] = (i==j ? 1.0 : 0.0) + sa*Wm[i][j] + sb*W2[i][j];
    }
    double dt[3];
    for (int i = 0; i < 3; i++)
      dt[i] = -(dR[i][0]*xi[3] + dR[i][1]*xi[4] + dR[i][2]*xi[5]);
    double Ro[3][3], to[3];
    for (int i = 0; i < 3; i++){
      for (int j = 0; j < 3; j++) Ro[i][j] = (double)pose[i*4+j];
      to[i] = (double)pose[i*4+3];
    }
    double Rn[3][3], tn[3];
    for (int i = 0; i < 3; i++){
      for (int j = 0; j < 3; j++)
        Rn[i][j] = dR[i][0]*Ro[0][j] + dR[i][1]*Ro[1][j] + dR[i][2]*Ro[2][j];
      tn[i] = dR[i][0]*to[0] + dR[i][1]*to[1] + dR[i][2]*to[2] + dt[i];
    }
    float o16[16];
    for (int i = 0; i < 3; i++){
      for (int j = 0; j < 3; j++) o16[i*4+j] = (float)Rn[i][j];
      o16[i*4+3] = (float)tn[i];
    }
    o16[12] = 0.f; o16[13] = 0.f; o16[14] = 0.f; o16[15] = 1.f;
    for (int k = 0; k < 16; k++){ pose[k] = o16[k]; outp[k] = o16[k]; }
  }
}

extern "C" void kernel_launch(void* const* d_in, const int* in_sizes, int n_in,
                              void* d_out, int out_size, void* d_ws, size_t ws_size,
                              hipStream_t stream) {
  const float* pose10 = (const float*)d_in[0];
  const float* depth0 = (const float*)d_in[1];
  const float* depth1 = (const float*)d_in[2];
  const float* x0     = (const float*)d_in[3];
  const float* x1     = (const float*)d_in[4];
  const float* Kd     = (const float*)d_in[5];
  char* ws = (char*)d_ws;
  float* pose    = (float*)(ws + WS_POSE_OFF);
  float* bmin    = (float*)(ws + WS_BMIN_OFF);
  float* bmax    = (float*)(ws + WS_BMAX_OFF);
  float* partial = (float*)(ws + WS_PARTIAL_OFF);
  float* nx1     = (float*)(ws + WS_NX_OFF);
  float* outp    = (float*)d_out;

  hipLaunchKernelGGL(k_pre1, dim3(MM_BLOCKS), dim3(256), 0, stream,
                     depth1, pose10, pose, bmin, bmax);
  hipLaunchKernelGGL(k_pre2, dim3(NBLK_ROW),  dim3(256), 0, stream,
                     depth1, x1, Kd, bmin, bmax, nx1);
  for (int it = 0; it < 3; it++){
    hipLaunchKernelGGL(k_main,  dim3(NBLK_MAIN), dim3(256), 0, stream,
                       depth0, x0, nx1, Kd, pose, partial);
    hipLaunchKernelGGL(k_solve, dim3(1),         dim3(256), 0, stream, partial, pose, outp);
  }
}